// Round 3
// baseline (193.692 us; speedup 1.0000x reference)
//
#include <hip/hip_runtime.h>
#include <math.h>

// Problem constants (SelectiveSSM)
#define BATCH   2
#define SEQLEN  512
#define DI      4096      // d_inner
#define DS      16        // d_state
#define RDT     128       // dt_rank
#define RTOT    160       // dt_rank + 2*d_state
#define BL      1024      // BATCH*SEQLEN rows

#define LOG2E 1.44269504088896340736f
#define LN2   0.69314718055994530942f

typedef __bf16 bf16;
typedef bf16  bf16x8 __attribute__((ext_vector_type(8)));
typedef float f32x4  __attribute__((ext_vector_type(4)));

__device__ __forceinline__ bf16x8 cvt8(const float4 a, const float4 b) {
  bf16x8 r;
  r[0] = (bf16)a.x; r[1] = (bf16)a.y; r[2] = (bf16)a.z; r[3] = (bf16)a.w;
  r[4] = (bf16)b.x; r[5] = (bf16)b.y; r[6] = (bf16)b.z; r[7] = (bf16)b.w;
  return r;
}

__device__ __forceinline__ bf16x8 cvt8s(const float4 a, const float4 b, const float s) {
  bf16x8 r;
  r[0] = (bf16)(s * a.x); r[1] = (bf16)(s * a.y); r[2] = (bf16)(s * a.z); r[3] = (bf16)(s * a.w);
  r[4] = (bf16)(s * b.x); r[5] = (bf16)(s * b.y); r[6] = (bf16)(s * b.z); r[7] = (bf16)(s * b.w);
  return r;
}

// ---------------------------------------------------------------------------
// GEMM1, single kernel, no atomics, no partial buffer.
// Grid: 64 blocks (one per 16-row M-tile) x 512 threads (8 waves).
// Wave w covers K slice [w*512, (w+1)*512); 16x160 partial in MFMA regs.
// Two-stage LDS reduce (waves 0-3 write, 4-7 add-in, then 4-way sum) and
// direct packed stores: cols 0..127 -> dtin bf16, cols 128..159 -> BCf fp32.
// W read fp32 with inline bf16 cvt (VALU has slack; avoids a cast kernel).
// ---------------------------------------------------------------------------
#define LPAD 164   // 164 mod 32 = 4: q-groups land on distinct banks

__global__ __launch_bounds__(512) void gemm_xp1(const float* __restrict__ x,
                                                const float* __restrict__ W,
                                                bf16* __restrict__ dtin,
                                                float* __restrict__ BCf) {
  __shared__ float Lred[4][16 * LPAD];   // 41,984 B
  const int tid = threadIdx.x;
  const int w = tid >> 6;                // 0..7
  const int lane = tid & 63;
  const int m = lane & 15;
  const int q = lane >> 4;
  const int row0 = blockIdx.x * 16;
  const int k0 = w * 512;

  f32x4 acc[10] = {};
  const float* ap = x + (size_t)(row0 + m) * DI + k0 + 8 * q;
  const float* wp = W + (size_t)m * DI + k0 + 8 * q;

  for (int kk = 0; kk < 512; kk += 32) {
    float4 a0 = *(const float4*)(ap + kk);
    float4 a1 = *(const float4*)(ap + kk + 4);
    bf16x8 af = cvt8(a0, a1);
#pragma unroll
    for (int nt = 0; nt < 10; ++nt) {
      const float* wq = wp + (size_t)nt * 16 * DI + kk;
      float4 b0 = *(const float4*)(wq);
      float4 b1 = *(const float4*)(wq + 4);
      acc[nt] = __builtin_amdgcn_mfma_f32_16x16x32_bf16(af, cvt8(b0, b1), acc[nt], 0, 0, 0);
    }
  }

  // C/D layout: col = m (N dim), row = 4q + r (M dim).
  if (w < 4) {
#pragma unroll
    for (int nt = 0; nt < 10; ++nt)
#pragma unroll
      for (int r = 0; r < 4; ++r)
        Lred[w][(4 * q + r) * LPAD + nt * 16 + m] = acc[nt][r];
  }
  __syncthreads();
  if (w >= 4) {
#pragma unroll
    for (int nt = 0; nt < 10; ++nt)
#pragma unroll
      for (int r = 0; r < 4; ++r)
        Lred[w - 4][(4 * q + r) * LPAD + nt * 16 + m] += acc[nt][r];
  }
  __syncthreads();

#pragma unroll
  for (int i = 0; i < 5; ++i) {
    const int o = i * 512 + tid;           // 0..2559 over 16x160 outputs
    const int row = o / 160;
    const int col = o - row * 160;
    const int a = row * LPAD + col;
    const float s = Lred[0][a] + Lred[1][a] + Lred[2][a] + Lred[3][a];
    if (col < RDT) dtin[(size_t)(row0 + row) * RDT + col] = (bf16)s;
    else           BCf[(size_t)(row0 + row) * 32 + (col - RDT)] = s;
  }
}

// ---------------------------------------------------------------------------
// 16-lane (DPP row) sum reduction on the VALU pipe. Result valid in lane 15
// of each 16-lane row. (old=0 + bound_ctrl=true is the canonical pattern the
// DPP combiner fuses into v_add_f32_dpp.)
// ---------------------------------------------------------------------------
__device__ __forceinline__ float row16_reduce_add(float p) {
  p += __int_as_float(__builtin_amdgcn_update_dpp(
      0, __float_as_int(p), 0x111, 0xf, 0xf, true));  // row_shr:1
  p += __int_as_float(__builtin_amdgcn_update_dpp(
      0, __float_as_int(p), 0x112, 0xf, 0xf, true));  // row_shr:2
  p += __int_as_float(__builtin_amdgcn_update_dpp(
      0, __float_as_int(p), 0x114, 0xf, 0xf, true));  // row_shr:4
  p += __int_as_float(__builtin_amdgcn_update_dpp(
      0, __float_as_int(p), 0x118, 0xf, 0xf, true));  // row_shr:8
  return p;
}

// ---------------------------------------------------------------------------
// Fused GEMM2 + selective scan (round-0 structure + fast-exp2 algebra).
//  - dtin bf16 fragments feed the dt MFMA directly (no inline cvt).
//  - dtw cast inline once, pre-scaled by log2(e); A pre-folded by log2(e) so
//    the per-step exponential is 1 mul + v_exp_f32 (__builtin_amdgcn_exp2f).
//  - D*x deferred out of the serial core to the y-store phase.
// ---------------------------------------------------------------------------
#define TC  64
#define TCP 68
#define NCH (SEQLEN / TC)

__global__ __launch_bounds__(256) void scan_fused(const float* __restrict__ x,
                                                  const float* __restrict__ A_log,
                                                  const float* __restrict__ Dvec,
                                                  const float* __restrict__ BCf,
                                                  const bf16* __restrict__ dtin,
                                                  const float* __restrict__ dtw,
                                                  const float* __restrict__ dtb,
                                                  float* __restrict__ out) {
  __shared__ __align__(16) float dtS[16][TCP];  // [dc][t]
  __shared__ __align__(16) float xS[16][TCP];   // [dc][t]
  __shared__ __align__(16) float BS[16][TCP];   // [n][t]
  __shared__ __align__(16) float CS[16][TCP];   // [n][t]
  __shared__ __align__(16) float yS[TC][16];    // [t][dc]

  const int bid = blockIdx.x;         // 0..511
  const int b = bid >> 8;
  const int d0 = (bid & 255) * 16;
  const int tid = threadIdx.x;
  const int n = tid & 15;             // state (scan) / MFMA m
  const int dc = tid >> 4;            // channel (scan)
  const int d = d0 + dc;
  const int w = tid >> 6;             // wave id (MFMA staging)
  const int m = tid & 15;
  const int q = (tid >> 4) & 3;

  const float A2 = -LOG2E * __expf(A_log[d * DS + n]);   // exp2-folded A
  const float bias2 = dtb[d0 + m] * LOG2E;

  // dtw B-fragments: chunk-invariant, scaled by log2e, cast inline (once)
  bf16x8 bfragW[4];
#pragma unroll
  for (int k = 0; k < 4; ++k) {
    const float* p = dtw + (size_t)(d0 + m) * RDT + 32 * k + 8 * q;
    float4 w0 = *(const float4*)p;
    float4 w1 = *(const float4*)(p + 4);
    bfragW[k] = cvt8s(w0, w1, LOG2E);
  }

  // loader mapping for x/B/C/y: thread -> row lt (0..63), 4-elem slice lf
  const int lt = tid >> 2;
  const int lf = (tid & 3) * 4;
  const int rowbase = b * SEQLEN;
  const float4 Dv4 = *(const float4*)&Dvec[d0 + lf];  // for deferred D*x

  // prefetch chunk 0
  bf16x8 afrag[4];
  float4 rx, rB, rC, rx_prev;
  {
    const int arow = rowbase + 16 * w + m;
#pragma unroll
    for (int k = 0; k < 4; ++k)
      afrag[k] = *(const bf16x8*)(dtin + (size_t)arow * RDT + 32 * k + 8 * q);
    const int row = rowbase + lt;
    rx = *(const float4*)&x[(size_t)row * DI + d0 + lf];
    rB = *(const float4*)&BCf[row * 32 + lf];
    rC = *(const float4*)&BCf[row * 32 + 16 + lf];
  }

  float h = 0.f;

  for (int c = 0; c < NCH; ++c) {
    if (c > 0) __syncthreads();   // prev compute (LDS reads + yS writes) done

    // ---- stage dt via MFMA + softplus (log2 domain, fast intrinsics) ----
    {
      f32x4 acc = {};
#pragma unroll
      for (int k = 0; k < 4; ++k)
        acc = __builtin_amdgcn_mfma_f32_16x16x32_bf16(afrag[k], bfragW[k], acc, 0, 0, 0);
      // D layout: col m = channel, row 4q+r = timestep within 16-row tile
#pragma unroll
      for (int r = 0; r < 4; ++r) {
        const float z2 = acc[r] + bias2;             // = z * log2(e)
        dtS[m][16 * w + 4 * q + r] =
            (z2 > 28.854f) ? z2 * LN2
                           : LN2 * __builtin_amdgcn_logf(1.f + __builtin_amdgcn_exp2f(z2));
      }
    }
    // ---- stage x, B, C (transposed) ----
    {
      const float rxa[4] = {rx.x, rx.y, rx.z, rx.w};
      const float rBa[4] = {rB.x, rB.y, rB.z, rB.w};
      const float rCa[4] = {rC.x, rC.y, rC.z, rC.w};
#pragma unroll
      for (int j = 0; j < 4; ++j) {
        xS[lf + j][lt] = rxa[j];
        BS[lf + j][lt] = rBa[j];
        CS[lf + j][lt] = rCa[j];
      }
    }
    // ---- store previous chunk's y (+ deferred D*x via rx_prev) ----
    if (c > 0) {
      const int prow = rowbase + (c - 1) * TC + lt;
      float4 yv = *(const float4*)&yS[lt][lf];
      float4 o4;
      o4.x = fmaf(Dv4.x, rx_prev.x, yv.x);
      o4.y = fmaf(Dv4.y, rx_prev.y, yv.y);
      o4.z = fmaf(Dv4.z, rx_prev.z, yv.z);
      o4.w = fmaf(Dv4.w, rx_prev.w, yv.w);
      *(float4*)&out[(size_t)prow * DI + d0 + lf] = o4;
    }
    rx_prev = rx;                 // keep chunk c's x for its y-store

    __syncthreads();              // tiles ready; yS reads done

    // ---- prefetch next chunk ----
    if (c < NCH - 1) {
      const int arow = rowbase + (c + 1) * TC + 16 * w + m;
#pragma unroll
      for (int k = 0; k < 4; ++k)
        afrag[k] = *(const bf16x8*)(dtin + (size_t)arow * RDT + 32 * k + 8 * q);
      const int row = rowbase + (c + 1) * TC + lt;
      rx = *(const float4*)&x[(size_t)row * DI + d0 + lf];
      rB = *(const float4*)&BCf[row * 32 + lf];
      rC = *(const float4*)&BCf[row * 32 + 16 + lf];
    }

    // ---- 64 steps: 8 groups of 8, explicit register batches ----
    for (int g = 0; g < 8; ++g) {
      const int t0 = 8 * g;
      const float4 dv0 = *(const float4*)&dtS[dc][t0];
      const float4 dv1 = *(const float4*)&dtS[dc][t0 + 4];
      const float4 xv0 = *(const float4*)&xS[dc][t0];
      const float4 xv1 = *(const float4*)&xS[dc][t0 + 4];
      const float4 Bv0 = *(const float4*)&BS[n][t0];
      const float4 Bv1 = *(const float4*)&BS[n][t0 + 4];
      const float4 Cv0 = *(const float4*)&CS[n][t0];
      const float4 Cv1 = *(const float4*)&CS[n][t0 + 4];
      const float dt[8] = {dv0.x, dv0.y, dv0.z, dv0.w, dv1.x, dv1.y, dv1.z, dv1.w};
      const float xv[8] = {xv0.x, xv0.y, xv0.z, xv0.w, xv1.x, xv1.y, xv1.z, xv1.w};
      const float Bv[8] = {Bv0.x, Bv0.y, Bv0.z, Bv0.w, Bv1.x, Bv1.y, Bv1.z, Bv1.w};
      const float Cv[8] = {Cv0.x, Cv0.y, Cv0.z, Cv0.w, Cv1.x, Cv1.y, Cv1.z, Cv1.w};

      float e[8], u[8], p[8];
#pragma unroll
      for (int j = 0; j < 8; ++j) {       // independent: pipelines freely
        e[j] = __builtin_amdgcn_exp2f(dt[j] * A2);   // 1 mul + v_exp_f32
        u[j] = dt[j] * xv[j] * Bv[j];
      }
#pragma unroll
      for (int j = 0; j < 8; ++j) {       // the only true serial chain
        h = fmaf(e[j], h, u[j]);
        p[j] = h * Cv[j];
      }
#pragma unroll
      for (int j = 0; j < 8; ++j)         // 8 independent DPP chains
        p[j] = row16_reduce_add(p[j]);
      if (n == 15) {
#pragma unroll
        for (int j = 0; j < 8; ++j)
          yS[t0 + j][dc] = p[j];          // D*x applied at store time
      }
    }
  }

  __syncthreads();
  {
    const int prow = rowbase + (NCH - 1) * TC + lt;
    float4 yv = *(const float4*)&yS[lt][lf];
    float4 o4;
    o4.x = fmaf(Dv4.x, rx_prev.x, yv.x);
    o4.y = fmaf(Dv4.y, rx_prev.y, yv.y);
    o4.z = fmaf(Dv4.z, rx_prev.z, yv.z);
    o4.w = fmaf(Dv4.w, rx_prev.w, yv.w);
    *(float4*)&out[(size_t)prow * DI + d0 + lf] = o4;
  }
}

// ---------------------------------------------------------------------------
extern "C" void kernel_launch(void* const* d_in, const int* in_sizes, int n_in,
                              void* d_out, int out_size, void* d_ws, size_t ws_size,
                              hipStream_t stream) {
  const float* x     = (const float*)d_in[0];  // (2,512,4096)
  const float* A_log = (const float*)d_in[1];  // (4096,16)
  const float* Dv    = (const float*)d_in[2];  // (4096,)
  const float* W     = (const float*)d_in[3];  // (160,4096)
  const float* dtw   = (const float*)d_in[4];  // (4096,128)
  const float* dtb   = (const float*)d_in[5];  // (4096,)
  float* out = (float*)d_out;

  // Workspace: dtin bf16 [1024][128] (256 KB) + BCf fp32 [1024][32] (128 KB)
  char* ws = (char*)d_ws;
  bf16*  dtin = (bf16*)ws;
  float* BCf  = (float*)(ws + 262144);

  gemm_xp1<<<dim3(64), 512, 0, stream>>>(x, W, dtin, BCf);
  scan_fused<<<dim3(512), 256, 0, stream>>>(x, A_log, Dv, BCf, dtin, dtw, dtb, out);
}

// Round 4
// 152.327 us; speedup vs baseline: 1.2716x; 1.2716x over previous
//
#include <hip/hip_runtime.h>
#include <math.h>

// Problem constants (SelectiveSSM)
#define BATCH   2
#define SEQLEN  512
#define DI      4096      // d_inner
#define DS      16        // d_state
#define RDT     128       // dt_rank
#define RTOT    160       // dt_rank + 2*d_state
#define BL      1024      // BATCH*SEQLEN rows

#define KSP     4         // k-split slabs (reduced by scan's linear consumers)

#define LOG2E 1.44269504088896340736f
#define LN2   0.69314718055994530942f

typedef __bf16 bf16;
typedef bf16  bf16x8 __attribute__((ext_vector_type(8)));
typedef float f32x4  __attribute__((ext_vector_type(4)));

__device__ __forceinline__ bf16x8 cvt8(const float4 a, const float4 b) {
  bf16x8 r;
  r[0] = (bf16)a.x; r[1] = (bf16)a.y; r[2] = (bf16)a.z; r[3] = (bf16)a.w;
  r[4] = (bf16)b.x; r[5] = (bf16)b.y; r[6] = (bf16)b.z; r[7] = (bf16)b.w;
  return r;
}

__device__ __forceinline__ bf16x8 cvt8s(const float4 a, const float4 b, const float s) {
  bf16x8 r;
  r[0] = (bf16)(s * a.x); r[1] = (bf16)(s * a.y); r[2] = (bf16)(s * a.z); r[3] = (bf16)(s * a.w);
  r[4] = (bf16)(s * b.x); r[5] = (bf16)(s * b.y); r[6] = (bf16)(s * b.z); r[7] = (bf16)(s * b.w);
  return r;
}

__device__ __forceinline__ float4 add4(float4 a, float4 b) {
  return make_float4(a.x + b.x, a.y + b.y, a.z + b.z, a.w + b.w);
}

// ---------------------------------------------------------------------------
// GEMM1 k-split partials. Grid (64 M-tiles x 4 k-splits) = 256 blocks x 512
// threads (8 waves). Wave w covers K slice [ks*1024 + w*128, +128) for the
// block's 16 rows; two-stage LDS reduce over the 8 waves; packed stores to
// slab ks: cols 0..127 -> dtp bf16, cols 128..159 -> bcp fp32. The slabs are
// NOT reduced here — the scan's consumers are linear in them (dt via MFMA
// accumulation, B/C via fp32 adds), so no reduce kernel / atomics / zeroing.
// W read fp32 with inline bf16 cvt (VALU is 2% busy; a cast kernel is a
// launch we don't need).
// ---------------------------------------------------------------------------
#define LPAD 164   // 164 mod 32 = 4: q-groups land on distinct banks

__global__ __launch_bounds__(512) void gemm_part(const float* __restrict__ x,
                                                 const float* __restrict__ W,
                                                 bf16* __restrict__ dtp,
                                                 float* __restrict__ bcp) {
  __shared__ float Lred[4][16 * LPAD];   // 41,984 B
  const int tid = threadIdx.x;
  const int w = tid >> 6;                // 0..7
  const int lane = tid & 63;
  const int m = lane & 15;
  const int q = lane >> 4;
  const int row0 = blockIdx.x * 16;
  const int ks = blockIdx.y;
  const int k0 = ks * (DI / KSP) + w * 128;

  f32x4 acc[10] = {};
  const float* ap = x + (size_t)(row0 + m) * DI + k0 + 8 * q;
  const float* wp = W + (size_t)m * DI + k0 + 8 * q;

#pragma unroll
  for (int kk = 0; kk < 128; kk += 32) {
    float4 a0 = *(const float4*)(ap + kk);
    float4 a1 = *(const float4*)(ap + kk + 4);
    bf16x8 af = cvt8(a0, a1);
#pragma unroll
    for (int nt = 0; nt < 10; ++nt) {
      const float* wq = wp + (size_t)nt * 16 * DI + kk;
      float4 b0 = *(const float4*)(wq);
      float4 b1 = *(const float4*)(wq + 4);
      acc[nt] = __builtin_amdgcn_mfma_f32_16x16x32_bf16(af, cvt8(b0, b1), acc[nt], 0, 0, 0);
    }
  }

  // C/D layout: col = m (N dim), row = 4q + r (M dim). Two-stage reduce.
  if (w < 4) {
#pragma unroll
    for (int nt = 0; nt < 10; ++nt)
#pragma unroll
      for (int r = 0; r < 4; ++r)
        Lred[w][(4 * q + r) * LPAD + nt * 16 + m] = acc[nt][r];
  }
  __syncthreads();
  if (w >= 4) {
#pragma unroll
    for (int nt = 0; nt < 10; ++nt)
#pragma unroll
      for (int r = 0; r < 4; ++r)
        Lred[w - 4][(4 * q + r) * LPAD + nt * 16 + m] += acc[nt][r];
  }
  __syncthreads();

#pragma unroll
  for (int i = 0; i < 5; ++i) {
    const int o = i * 512 + tid;           // 0..2559 over 16x160 outputs
    const int row = o / 160;
    const int col = o - row * 160;
    const int a = row * LPAD + col;
    const float s = Lred[0][a] + Lred[1][a] + Lred[2][a] + Lred[3][a];
    if (col < RDT) dtp[(size_t)ks * (BL * RDT) + (size_t)(row0 + row) * RDT + col] = (bf16)s;
    else           bcp[(size_t)ks * (BL * 32) + (size_t)(row0 + row) * 32 + (col - RDT)] = s;
  }
}

// ---------------------------------------------------------------------------
// 16-lane (DPP row) sum reduction on the VALU pipe. Result valid in lane 15
// of each 16-lane row.
// ---------------------------------------------------------------------------
__device__ __forceinline__ float row16_reduce_add(float p) {
  p += __int_as_float(__builtin_amdgcn_update_dpp(
      0, __float_as_int(p), 0x111, 0xf, 0xf, true));  // row_shr:1
  p += __int_as_float(__builtin_amdgcn_update_dpp(
      0, __float_as_int(p), 0x112, 0xf, 0xf, true));  // row_shr:2
  p += __int_as_float(__builtin_amdgcn_update_dpp(
      0, __float_as_int(p), 0x114, 0xf, 0xf, true));  // row_shr:4
  p += __int_as_float(__builtin_amdgcn_update_dpp(
      0, __float_as_int(p), 0x118, 0xf, 0xf, true));  // row_shr:8
  return p;
}

// ---------------------------------------------------------------------------
// Fused GEMM2 + selective scan (round-3 structure, slab-summing inputs).
//  - dt MFMA accumulates over the 4 k-split slabs (linear => exact fp32 sum).
//  - B/C summed from 4 fp32 slabs at prefetch time.
//  - dtw pre-scaled by log2(e); per-step exponential = 1 mul + v_exp_f32.
//  - D*x deferred out of the serial core to the y-store phase.
// ---------------------------------------------------------------------------
#define TC  64
#define TCP 68
#define NCH (SEQLEN / TC)

__global__ __launch_bounds__(256) void scan_fused(const float* __restrict__ x,
                                                  const float* __restrict__ A_log,
                                                  const float* __restrict__ Dvec,
                                                  const float* __restrict__ bcp,
                                                  const bf16* __restrict__ dtp,
                                                  const float* __restrict__ dtw,
                                                  const float* __restrict__ dtb,
                                                  float* __restrict__ out) {
  __shared__ __align__(16) float dtS[16][TCP];  // [dc][t]
  __shared__ __align__(16) float xS[16][TCP];   // [dc][t]
  __shared__ __align__(16) float BS[16][TCP];   // [n][t]
  __shared__ __align__(16) float CS[16][TCP];   // [n][t]
  __shared__ __align__(16) float yS[TC][16];    // [t][dc]

  const int bid = blockIdx.x;         // 0..511
  const int b = bid >> 8;
  const int d0 = (bid & 255) * 16;
  const int tid = threadIdx.x;
  const int n = tid & 15;             // state (scan) / MFMA m
  const int dc = tid >> 4;            // channel (scan)
  const int d = d0 + dc;
  const int w = tid >> 6;             // wave id (MFMA staging)
  const int m = tid & 15;
  const int q = (tid >> 4) & 3;

  const float A2 = -LOG2E * __expf(A_log[d * DS + n]);   // exp2-folded A
  const float bias2 = dtb[d0 + m] * LOG2E;

  // dtw B-fragments: chunk-invariant, scaled by log2e, cast inline (once)
  bf16x8 bfragW[4];
#pragma unroll
  for (int k = 0; k < 4; ++k) {
    const float* p = dtw + (size_t)(d0 + m) * RDT + 32 * k + 8 * q;
    float4 w0 = *(const float4*)p;
    float4 w1 = *(const float4*)(p + 4);
    bfragW[k] = cvt8s(w0, w1, LOG2E);
  }

  // loader mapping for x/B/C/y: thread -> row lt (0..63), 4-elem slice lf
  const int lt = tid >> 2;
  const int lf = (tid & 3) * 4;
  const int rowbase = b * SEQLEN;
  const float4 Dv4 = *(const float4*)&Dvec[d0 + lf];  // for deferred D*x

  // prefetch chunk 0
  bf16x8 afrag[KSP][4];
  float4 rx, rB, rC, rx_prev;
  {
    const int arow = rowbase + 16 * w + m;
#pragma unroll
    for (int ks = 0; ks < KSP; ++ks)
#pragma unroll
      for (int k = 0; k < 4; ++k)
        afrag[ks][k] = *(const bf16x8*)(dtp + (size_t)ks * (BL * RDT) +
                                        (size_t)arow * RDT + 32 * k + 8 * q);
    const int row = rowbase + lt;
    rx = *(const float4*)&x[(size_t)row * DI + d0 + lf];
    rB = *(const float4*)&bcp[row * 32 + lf];
    rC = *(const float4*)&bcp[row * 32 + 16 + lf];
#pragma unroll
    for (int ks = 1; ks < KSP; ++ks) {
      rB = add4(rB, *(const float4*)&bcp[(size_t)ks * (BL * 32) + row * 32 + lf]);
      rC = add4(rC, *(const float4*)&bcp[(size_t)ks * (BL * 32) + row * 32 + 16 + lf]);
    }
  }

  float h = 0.f;

  for (int c = 0; c < NCH; ++c) {
    if (c > 0) __syncthreads();   // prev compute (LDS reads + yS writes) done

    // ---- stage dt via MFMA over slabs + softplus (log2 domain) ----
    {
      f32x4 acc = {};
#pragma unroll
      for (int ks = 0; ks < KSP; ++ks)
#pragma unroll
        for (int k = 0; k < 4; ++k)
          acc = __builtin_amdgcn_mfma_f32_16x16x32_bf16(afrag[ks][k], bfragW[k], acc, 0, 0, 0);
      // D layout: col m = channel, row 4q+r = timestep within 16-row tile
#pragma unroll
      for (int r = 0; r < 4; ++r) {
        const float z2 = acc[r] + bias2;             // = z * log2(e)
        dtS[m][16 * w + 4 * q + r] =
            (z2 > 28.854f) ? z2 * LN2
                           : LN2 * __builtin_amdgcn_logf(1.f + __builtin_amdgcn_exp2f(z2));
      }
    }
    // ---- stage x, B, C (transposed) ----
    {
      const float rxa[4] = {rx.x, rx.y, rx.z, rx.w};
      const float rBa[4] = {rB.x, rB.y, rB.z, rB.w};
      const float rCa[4] = {rC.x, rC.y, rC.z, rC.w};
#pragma unroll
      for (int j = 0; j < 4; ++j) {
        xS[lf + j][lt] = rxa[j];
        BS[lf + j][lt] = rBa[j];
        CS[lf + j][lt] = rCa[j];
      }
    }
    // ---- store previous chunk's y (+ deferred D*x via rx_prev) ----
    if (c > 0) {
      const int prow = rowbase + (c - 1) * TC + lt;
      float4 yv = *(const float4*)&yS[lt][lf];
      float4 o4;
      o4.x = fmaf(Dv4.x, rx_prev.x, yv.x);
      o4.y = fmaf(Dv4.y, rx_prev.y, yv.y);
      o4.z = fmaf(Dv4.z, rx_prev.z, yv.z);
      o4.w = fmaf(Dv4.w, rx_prev.w, yv.w);
      *(float4*)&out[(size_t)prow * DI + d0 + lf] = o4;
    }
    rx_prev = rx;                 // keep chunk c's x for its y-store

    __syncthreads();              // tiles ready; yS reads done

    // ---- prefetch next chunk ----
    if (c < NCH - 1) {
      const int arow = rowbase + (c + 1) * TC + 16 * w + m;
#pragma unroll
      for (int ks = 0; ks < KSP; ++ks)
#pragma unroll
        for (int k = 0; k < 4; ++k)
          afrag[ks][k] = *(const bf16x8*)(dtp + (size_t)ks * (BL * RDT) +
                                          (size_t)arow * RDT + 32 * k + 8 * q);
      const int row = rowbase + (c + 1) * TC + lt;
      rx = *(const float4*)&x[(size_t)row * DI + d0 + lf];
      rB = *(const float4*)&bcp[row * 32 + lf];
      rC = *(const float4*)&bcp[row * 32 + 16 + lf];
#pragma unroll
      for (int ks = 1; ks < KSP; ++ks) {
        rB = add4(rB, *(const float4*)&bcp[(size_t)ks * (BL * 32) + row * 32 + lf]);
        rC = add4(rC, *(const float4*)&bcp[(size_t)ks * (BL * 32) + row * 32 + 16 + lf]);
      }
    }

    // ---- 64 steps: 8 groups of 8, explicit register batches ----
    for (int g = 0; g < 8; ++g) {
      const int t0 = 8 * g;
      const float4 dv0 = *(const float4*)&dtS[dc][t0];
      const float4 dv1 = *(const float4*)&dtS[dc][t0 + 4];
      const float4 xv0 = *(const float4*)&xS[dc][t0];
      const float4 xv1 = *(const float4*)&xS[dc][t0 + 4];
      const float4 Bv0 = *(const float4*)&BS[n][t0];
      const float4 Bv1 = *(const float4*)&BS[n][t0 + 4];
      const float4 Cv0 = *(const float4*)&CS[n][t0];
      const float4 Cv1 = *(const float4*)&CS[n][t0 + 4];
      const float dt[8] = {dv0.x, dv0.y, dv0.z, dv0.w, dv1.x, dv1.y, dv1.z, dv1.w};
      const float xv[8] = {xv0.x, xv0.y, xv0.z, xv0.w, xv1.x, xv1.y, xv1.z, xv1.w};
      const float Bv[8] = {Bv0.x, Bv0.y, Bv0.z, Bv0.w, Bv1.x, Bv1.y, Bv1.z, Bv1.w};
      const float Cv[8] = {Cv0.x, Cv0.y, Cv0.z, Cv0.w, Cv1.x, Cv1.y, Cv1.z, Cv1.w};

      float e[8], u[8], p[8];
#pragma unroll
      for (int j = 0; j < 8; ++j) {       // independent: pipelines freely
        e[j] = __builtin_amdgcn_exp2f(dt[j] * A2);   // 1 mul + v_exp_f32
        u[j] = dt[j] * xv[j] * Bv[j];
      }
#pragma unroll
      for (int j = 0; j < 8; ++j) {       // the only true serial chain
        h = fmaf(e[j], h, u[j]);
        p[j] = h * Cv[j];
      }
#pragma unroll
      for (int j = 0; j < 8; ++j)         // 8 independent DPP chains
        p[j] = row16_reduce_add(p[j]);
      if (n == 15) {
#pragma unroll
        for (int j = 0; j < 8; ++j)
          yS[t0 + j][dc] = p[j];          // D*x applied at store time
      }
    }
  }

  __syncthreads();
  {
    const int prow = rowbase + (NCH - 1) * TC + lt;
    float4 yv = *(const float4*)&yS[lt][lf];
    float4 o4;
    o4.x = fmaf(Dv4.x, rx_prev.x, yv.x);
    o4.y = fmaf(Dv4.y, rx_prev.y, yv.y);
    o4.z = fmaf(Dv4.z, rx_prev.z, yv.z);
    o4.w = fmaf(Dv4.w, rx_prev.w, yv.w);
    *(float4*)&out[(size_t)prow * DI + d0 + lf] = o4;
  }
}

// ---------------------------------------------------------------------------
extern "C" void kernel_launch(void* const* d_in, const int* in_sizes, int n_in,
                              void* d_out, int out_size, void* d_ws, size_t ws_size,
                              hipStream_t stream) {
  const float* x     = (const float*)d_in[0];  // (2,512,4096)
  const float* A_log = (const float*)d_in[1];  // (4096,16)
  const float* Dv    = (const float*)d_in[2];  // (4096,)
  const float* W     = (const float*)d_in[3];  // (160,4096)
  const float* dtw   = (const float*)d_in[4];  // (4096,128)
  const float* dtb   = (const float*)d_in[5];  // (4096,)
  float* out = (float*)d_out;

  // Workspace: dtp bf16 [4][1024][128] (1 MB) + bcp fp32 [4][1024][32] (512 KB)
  char* ws = (char*)d_ws;
  bf16*  dtp = (bf16*)ws;
  float* bcp = (float*)(ws + (size_t)KSP * BL * RDT * sizeof(bf16));

  gemm_part<<<dim3(64, KSP), 512, 0, stream>>>(x, W, dtp, bcp);
  scan_fused<<<dim3(512), 256, 0, stream>>>(x, A_log, Dv, bcp, dtp, dtw, dtb, out);
}

// Round 5
// 136.451 us; speedup vs baseline: 1.4195x; 1.1163x over previous
//
#include <hip/hip_runtime.h>
#include <math.h>

// Problem constants (SelectiveSSM)
#define BATCH   2
#define SEQLEN  512
#define DI      4096      // d_inner
#define DS      16        // d_state
#define RDT     128       // dt_rank
#define RTOT    160       // dt_rank + 2*d_state
#define BL      1024      // BATCH*SEQLEN rows

#define KSP     4         // k-split slabs

#define LOG2E 1.44269504088896340736f
#define LN2   0.69314718055994530942f

typedef __bf16 bf16;
typedef bf16  bf16x8 __attribute__((ext_vector_type(8)));
typedef bf16  bf16x4 __attribute__((ext_vector_type(4)));
typedef float f32x4  __attribute__((ext_vector_type(4)));

__device__ __forceinline__ bf16x8 cvt8(const float4 a, const float4 b) {
  bf16x8 r;
  r[0] = (bf16)a.x; r[1] = (bf16)a.y; r[2] = (bf16)a.z; r[3] = (bf16)a.w;
  r[4] = (bf16)b.x; r[5] = (bf16)b.y; r[6] = (bf16)b.z; r[7] = (bf16)b.w;
  return r;
}

__device__ __forceinline__ bf16x8 cvt8s(const float4 a, const float4 b, const float s) {
  bf16x8 r;
  r[0] = (bf16)(s * a.x); r[1] = (bf16)(s * a.y); r[2] = (bf16)(s * a.z); r[3] = (bf16)(s * a.w);
  r[4] = (bf16)(s * b.x); r[5] = (bf16)(s * b.y); r[6] = (bf16)(s * b.z); r[7] = (bf16)(s * b.w);
  return r;
}

// ---------------------------------------------------------------------------
// GEMM1 k-split partials. Grid (64 M-tiles x 4 k-splits) = 256 blocks x 512
// threads (8 waves) — full CU coverage, 8 waves/CU. Wave w covers K slice
// [ks*1024 + w*128, +128); two-stage LDS reduce over the 8 waves; packed
// stores to slab ks: cols 0..127 -> dtp bf16, cols 128..159 -> bcp fp32.
// (Proven < 62 µs in round 4 vs 101 µs for the 64-block monolith.)
// ---------------------------------------------------------------------------
#define LPAD 164   // 164 mod 32 = 4: q-groups land on distinct banks

__global__ __launch_bounds__(512) void gemm_part(const float* __restrict__ x,
                                                 const float* __restrict__ W,
                                                 bf16* __restrict__ dtp,
                                                 float* __restrict__ bcp) {
  __shared__ float Lred[4][16 * LPAD];   // 41,984 B
  const int tid = threadIdx.x;
  const int w = tid >> 6;                // 0..7
  const int lane = tid & 63;
  const int m = lane & 15;
  const int q = lane >> 4;
  const int row0 = blockIdx.x * 16;
  const int ks = blockIdx.y;
  const int k0 = ks * (DI / KSP) + w * 128;

  f32x4 acc[10] = {};
  const float* ap = x + (size_t)(row0 + m) * DI + k0 + 8 * q;
  const float* wp = W + (size_t)m * DI + k0 + 8 * q;

#pragma unroll
  for (int kk = 0; kk < 128; kk += 32) {
    float4 a0 = *(const float4*)(ap + kk);
    float4 a1 = *(const float4*)(ap + kk + 4);
    bf16x8 af = cvt8(a0, a1);
#pragma unroll
    for (int nt = 0; nt < 10; ++nt) {
      const float* wq = wp + (size_t)nt * 16 * DI + kk;
      float4 b0 = *(const float4*)(wq);
      float4 b1 = *(const float4*)(wq + 4);
      acc[nt] = __builtin_amdgcn_mfma_f32_16x16x32_bf16(af, cvt8(b0, b1), acc[nt], 0, 0, 0);
    }
  }

  // C/D layout: col = m (N dim), row = 4q + r (M dim). Two-stage reduce.
  if (w < 4) {
#pragma unroll
    for (int nt = 0; nt < 10; ++nt)
#pragma unroll
      for (int r = 0; r < 4; ++r)
        Lred[w][(4 * q + r) * LPAD + nt * 16 + m] = acc[nt][r];
  }
  __syncthreads();
  if (w >= 4) {
#pragma unroll
    for (int nt = 0; nt < 10; ++nt)
#pragma unroll
      for (int r = 0; r < 4; ++r)
        Lred[w - 4][(4 * q + r) * LPAD + nt * 16 + m] += acc[nt][r];
  }
  __syncthreads();

#pragma unroll
  for (int i = 0; i < 5; ++i) {
    const int o = i * 512 + tid;           // 0..2559 over 16x160 outputs
    const int row = o / 160;
    const int col = o - row * 160;
    const int a = row * LPAD + col;
    const float s = Lred[0][a] + Lred[1][a] + Lred[2][a] + Lred[3][a];
    if (col < RDT) dtp[(size_t)ks * (BL * RDT) + (size_t)(row0 + row) * RDT + col] = (bf16)s;
    else           bcp[(size_t)ks * (BL * 32) + (size_t)(row0 + row) * 32 + (col - RDT)] = s;
  }
}

// ---------------------------------------------------------------------------
// Fold the 4 k-split slabs into the scan's compact inputs:
//   dtin bf16 [1024][128], BCf fp32 [1024][32].
// 160 blocks x 256 threads, 4 outputs/thread; ~6 MB L2-resident reads.
// This keeps the slab-sum OFF the serial-critical scan kernel (round-4
// lesson: folding it into the scan cost +38 VGPR, +5 MB FETCH, +17 µs).
// ---------------------------------------------------------------------------
__global__ __launch_bounds__(256) void reduce_slabs(const bf16* __restrict__ dtp,
                                                    const float* __restrict__ bcp,
                                                    bf16* __restrict__ dtin,
                                                    float* __restrict__ BCf) {
  const int o = (blockIdx.x * 256 + threadIdx.x) * 4;
  const int row = o / RTOT;
  const int col = o - row * RTOT;   // multiple of 4; never straddles rows
  if (col < RDT) {
    float s0 = 0.f, s1 = 0.f, s2 = 0.f, s3 = 0.f;
#pragma unroll
    for (int ks = 0; ks < KSP; ++ks) {
      bf16x4 v = *(const bf16x4*)(dtp + (size_t)ks * (BL * RDT) + (size_t)row * RDT + col);
      s0 += (float)v[0]; s1 += (float)v[1]; s2 += (float)v[2]; s3 += (float)v[3];
    }
    bf16x4 ob;
    ob[0] = (bf16)s0; ob[1] = (bf16)s1; ob[2] = (bf16)s2; ob[3] = (bf16)s3;
    *(bf16x4*)(dtin + (size_t)row * RDT + col) = ob;
  } else {
    float4 s = make_float4(0.f, 0.f, 0.f, 0.f);
#pragma unroll
    for (int ks = 0; ks < KSP; ++ks) {
      float4 v = *(const float4*)&bcp[(size_t)ks * (BL * 32) + (size_t)row * 32 + (col - RDT)];
      s.x += v.x; s.y += v.y; s.z += v.z; s.w += v.w;
    }
    *(float4*)&BCf[(size_t)row * 32 + (col - RDT)] = s;
  }
}

// ---------------------------------------------------------------------------
// 16-lane (DPP row) sum reduction on the VALU pipe. Result valid in lane 15
// of each 16-lane row.
// ---------------------------------------------------------------------------
__device__ __forceinline__ float row16_reduce_add(float p) {
  p += __int_as_float(__builtin_amdgcn_update_dpp(
      0, __float_as_int(p), 0x111, 0xf, 0xf, true));  // row_shr:1
  p += __int_as_float(__builtin_amdgcn_update_dpp(
      0, __float_as_int(p), 0x112, 0xf, 0xf, true));  // row_shr:2
  p += __int_as_float(__builtin_amdgcn_update_dpp(
      0, __float_as_int(p), 0x114, 0xf, 0xf, true));  // row_shr:4
  p += __int_as_float(__builtin_amdgcn_update_dpp(
      0, __float_as_int(p), 0x118, 0xf, 0xf, true));  // row_shr:8
  return p;
}

// ---------------------------------------------------------------------------
// Fused GEMM2 + selective scan (round-3 structure: compact reduced inputs,
// afrag[4] only, ~64 VGPR).
//  - dtin bf16 fragments feed the dt MFMA directly.
//  - dtw pre-scaled by log2(e); per-step exponential = 1 mul + v_exp_f32.
//  - D*x deferred out of the serial core to the y-store phase.
// ---------------------------------------------------------------------------
#define TC  64
#define TCP 68
#define NCH (SEQLEN / TC)

__global__ __launch_bounds__(256) void scan_fused(const float* __restrict__ x,
                                                  const float* __restrict__ A_log,
                                                  const float* __restrict__ Dvec,
                                                  const float* __restrict__ BCf,
                                                  const bf16* __restrict__ dtin,
                                                  const float* __restrict__ dtw,
                                                  const float* __restrict__ dtb,
                                                  float* __restrict__ out) {
  __shared__ __align__(16) float dtS[16][TCP];  // [dc][t]
  __shared__ __align__(16) float xS[16][TCP];   // [dc][t]
  __shared__ __align__(16) float BS[16][TCP];   // [n][t]
  __shared__ __align__(16) float CS[16][TCP];   // [n][t]
  __shared__ __align__(16) float yS[TC][16];    // [t][dc]

  const int bid = blockIdx.x;         // 0..511
  const int b = bid >> 8;
  const int d0 = (bid & 255) * 16;
  const int tid = threadIdx.x;
  const int n = tid & 15;             // state (scan) / MFMA m
  const int dc = tid >> 4;            // channel (scan)
  const int d = d0 + dc;
  const int w = tid >> 6;             // wave id (MFMA staging)
  const int m = tid & 15;
  const int q = (tid >> 4) & 3;

  const float A2 = -LOG2E * __expf(A_log[d * DS + n]);   // exp2-folded A
  const float bias2 = dtb[d0 + m] * LOG2E;

  // dtw B-fragments: chunk-invariant, scaled by log2e, cast inline (once)
  bf16x8 bfragW[4];
#pragma unroll
  for (int k = 0; k < 4; ++k) {
    const float* p = dtw + (size_t)(d0 + m) * RDT + 32 * k + 8 * q;
    float4 w0 = *(const float4*)p;
    float4 w1 = *(const float4*)(p + 4);
    bfragW[k] = cvt8s(w0, w1, LOG2E);
  }

  // loader mapping for x/B/C/y: thread -> row lt (0..63), 4-elem slice lf
  const int lt = tid >> 2;
  const int lf = (tid & 3) * 4;
  const int rowbase = b * SEQLEN;
  const float4 Dv4 = *(const float4*)&Dvec[d0 + lf];  // for deferred D*x

  // prefetch chunk 0
  bf16x8 afrag[4];
  float4 rx, rB, rC, rx_prev;
  {
    const int arow = rowbase + 16 * w + m;
#pragma unroll
    for (int k = 0; k < 4; ++k)
      afrag[k] = *(const bf16x8*)(dtin + (size_t)arow * RDT + 32 * k + 8 * q);
    const int row = rowbase + lt;
    rx = *(const float4*)&x[(size_t)row * DI + d0 + lf];
    rB = *(const float4*)&BCf[row * 32 + lf];
    rC = *(const float4*)&BCf[row * 32 + 16 + lf];
  }

  float h = 0.f;

  for (int c = 0; c < NCH; ++c) {
    if (c > 0) __syncthreads();   // prev compute (LDS reads + yS writes) done

    // ---- stage dt via MFMA + softplus (log2 domain, fast intrinsics) ----
    {
      f32x4 acc = {};
#pragma unroll
      for (int k = 0; k < 4; ++k)
        acc = __builtin_amdgcn_mfma_f32_16x16x32_bf16(afrag[k], bfragW[k], acc, 0, 0, 0);
      // D layout: col m = channel, row 4q+r = timestep within 16-row tile
#pragma unroll
      for (int r = 0; r < 4; ++r) {
        const float z2 = acc[r] + bias2;             // = z * log2(e)
        dtS[m][16 * w + 4 * q + r] =
            (z2 > 28.854f) ? z2 * LN2
                           : LN2 * __builtin_amdgcn_logf(1.f + __builtin_amdgcn_exp2f(z2));
      }
    }
    // ---- stage x, B, C (transposed) ----
    {
      const float rxa[4] = {rx.x, rx.y, rx.z, rx.w};
      const float rBa[4] = {rB.x, rB.y, rB.z, rB.w};
      const float rCa[4] = {rC.x, rC.y, rC.z, rC.w};
#pragma unroll
      for (int j = 0; j < 4; ++j) {
        xS[lf + j][lt] = rxa[j];
        BS[lf + j][lt] = rBa[j];
        CS[lf + j][lt] = rCa[j];
      }
    }
    // ---- store previous chunk's y (+ deferred D*x via rx_prev) ----
    if (c > 0) {
      const int prow = rowbase + (c - 1) * TC + lt;
      float4 yv = *(const float4*)&yS[lt][lf];
      float4 o4;
      o4.x = fmaf(Dv4.x, rx_prev.x, yv.x);
      o4.y = fmaf(Dv4.y, rx_prev.y, yv.y);
      o4.z = fmaf(Dv4.z, rx_prev.z, yv.z);
      o4.w = fmaf(Dv4.w, rx_prev.w, yv.w);
      *(float4*)&out[(size_t)prow * DI + d0 + lf] = o4;
    }
    rx_prev = rx;                 // keep chunk c's x for its y-store

    __syncthreads();              // tiles ready; yS reads done

    // ---- prefetch next chunk ----
    if (c < NCH - 1) {
      const int arow = rowbase + (c + 1) * TC + 16 * w + m;
#pragma unroll
      for (int k = 0; k < 4; ++k)
        afrag[k] = *(const bf16x8*)(dtin + (size_t)arow * RDT + 32 * k + 8 * q);
      const int row = rowbase + (c + 1) * TC + lt;
      rx = *(const float4*)&x[(size_t)row * DI + d0 + lf];
      rB = *(const float4*)&BCf[row * 32 + lf];
      rC = *(const float4*)&BCf[row * 32 + 16 + lf];
    }

    // ---- 64 steps: 8 groups of 8, explicit register batches ----
    for (int g = 0; g < 8; ++g) {
      const int t0 = 8 * g;
      const float4 dv0 = *(const float4*)&dtS[dc][t0];
      const float4 dv1 = *(const float4*)&dtS[dc][t0 + 4];
      const float4 xv0 = *(const float4*)&xS[dc][t0];
      const float4 xv1 = *(const float4*)&xS[dc][t0 + 4];
      const float4 Bv0 = *(const float4*)&BS[n][t0];
      const float4 Bv1 = *(const float4*)&BS[n][t0 + 4];
      const float4 Cv0 = *(const float4*)&CS[n][t0];
      const float4 Cv1 = *(const float4*)&CS[n][t0 + 4];
      const float dt[8] = {dv0.x, dv0.y, dv0.z, dv0.w, dv1.x, dv1.y, dv1.z, dv1.w};
      const float xv[8] = {xv0.x, xv0.y, xv0.z, xv0.w, xv1.x, xv1.y, xv1.z, xv1.w};
      const float Bv[8] = {Bv0.x, Bv0.y, Bv0.z, Bv0.w, Bv1.x, Bv1.y, Bv1.z, Bv1.w};
      const float Cv[8] = {Cv0.x, Cv0.y, Cv0.z, Cv0.w, Cv1.x, Cv1.y, Cv1.z, Cv1.w};

      float e[8], u[8], p[8];
#pragma unroll
      for (int j = 0; j < 8; ++j) {       // independent: pipelines freely
        e[j] = __builtin_amdgcn_exp2f(dt[j] * A2);   // 1 mul + v_exp_f32
        u[j] = dt[j] * xv[j] * Bv[j];
      }
#pragma unroll
      for (int j = 0; j < 8; ++j) {       // the only true serial chain
        h = fmaf(e[j], h, u[j]);
        p[j] = h * Cv[j];
      }
#pragma unroll
      for (int j = 0; j < 8; ++j)         // 8 independent DPP chains
        p[j] = row16_reduce_add(p[j]);
      if (n == 15) {
#pragma unroll
        for (int j = 0; j < 8; ++j)
          yS[t0 + j][dc] = p[j];          // D*x applied at store time
      }
    }
  }

  __syncthreads();
  {
    const int prow = rowbase + (NCH - 1) * TC + lt;
    float4 yv = *(const float4*)&yS[lt][lf];
    float4 o4;
    o4.x = fmaf(Dv4.x, rx_prev.x, yv.x);
    o4.y = fmaf(Dv4.y, rx_prev.y, yv.y);
    o4.z = fmaf(Dv4.z, rx_prev.z, yv.z);
    o4.w = fmaf(Dv4.w, rx_prev.w, yv.w);
    *(float4*)&out[(size_t)prow * DI + d0 + lf] = o4;
  }
}

// ---------------------------------------------------------------------------
extern "C" void kernel_launch(void* const* d_in, const int* in_sizes, int n_in,
                              void* d_out, int out_size, void* d_ws, size_t ws_size,
                              hipStream_t stream) {
  const float* x     = (const float*)d_in[0];  // (2,512,4096)
  const float* A_log = (const float*)d_in[1];  // (4096,16)
  const float* Dv    = (const float*)d_in[2];  // (4096,)
  const float* W     = (const float*)d_in[3];  // (160,4096)
  const float* dtw   = (const float*)d_in[4];  // (4096,128)
  const float* dtb   = (const float*)d_in[5];  // (4096,)
  float* out = (float*)d_out;

  // Workspace: dtp [4][1024][128] bf16 (1 MB) + bcp [4][1024][32] f32 (512 KB)
  //          + dtin [1024][128] bf16 (256 KB) + BCf [1024][32] f32 (128 KB)
  char* ws = (char*)d_ws;
  bf16*  dtp  = (bf16*)ws;
  float* bcp  = (float*)(ws + (size_t)KSP * BL * RDT * sizeof(bf16));
  bf16*  dtin = (bf16*)(ws + (size_t)KSP * BL * RDT * sizeof(bf16)
                           + (size_t)KSP * BL * 32 * sizeof(float));
  float* BCf  = (float*)(ws + (size_t)KSP * BL * RDT * sizeof(bf16)
                            + (size_t)KSP * BL * 32 * sizeof(float)
                            + (size_t)BL * RDT * sizeof(bf16));

  gemm_part<<<dim3(64, KSP), 512, 0, stream>>>(x, W, dtp, bcp);
  reduce_slabs<<<dim3(160), 256, 0, stream>>>(dtp, bcp, dtin, BCf);
  scan_fused<<<dim3(512), 256, 0, stream>>>(x, A_log, Dv, BCf, dtin, dtw, dtb, out);
}

// Round 6
// 135.453 us; speedup vs baseline: 1.4300x; 1.0074x over previous
//
#include <hip/hip_runtime.h>
#include <math.h>

// Problem constants (SelectiveSSM)
#define BATCH   2
#define SEQLEN  512
#define DI      4096      // d_inner
#define DS      16        // d_state
#define RDT     128       // dt_rank
#define RTOT    160       // dt_rank + 2*d_state
#define BL      1024      // BATCH*SEQLEN rows

#define KSP     8         // k-split slabs (512-wide each)

#define LOG2E 1.44269504088896340736f
#define LN2   0.69314718055994530942f

typedef __bf16 bf16;
typedef bf16  bf16x8 __attribute__((ext_vector_type(8)));
typedef bf16  bf16x4 __attribute__((ext_vector_type(4)));
typedef float f32x4  __attribute__((ext_vector_type(4)));

__device__ __forceinline__ bf16x8 cvt8(const float4 a, const float4 b) {
  bf16x8 r;
  r[0] = (bf16)a.x; r[1] = (bf16)a.y; r[2] = (bf16)a.z; r[3] = (bf16)a.w;
  r[4] = (bf16)b.x; r[5] = (bf16)b.y; r[6] = (bf16)b.z; r[7] = (bf16)b.w;
  return r;
}

__device__ __forceinline__ bf16x8 cvt8s(const float4 a, const float4 b, const float s) {
  bf16x8 r;
  r[0] = (bf16)(s * a.x); r[1] = (bf16)(s * a.y); r[2] = (bf16)(s * a.z); r[3] = (bf16)(s * a.w);
  r[4] = (bf16)(s * b.x); r[5] = (bf16)(s * b.y); r[6] = (bf16)(s * b.z); r[7] = (bf16)(s * b.w);
  return r;
}

// ---------------------------------------------------------------------------
// GEMM1 k-split partials. Grid (64 M-tiles x 8 k-splits) = 512 blocks x 512
// threads — 2 blocks/CU, 4 waves/SIMD (double round-5's latency hiding;
// round 3->4 showed this kernel is load-latency-bound). Wave w covers K
// slice [ks*512 + w*64, +64); two-stage LDS reduce over the 8 waves; packed
// stores to slab ks: cols 0..127 -> dtp bf16, cols 128..159 -> bcp fp32.
// ---------------------------------------------------------------------------
#define LPAD 164   // 164 mod 32 = 4: q-groups land on distinct banks

__global__ __launch_bounds__(512) void gemm_part(const float* __restrict__ x,
                                                 const float* __restrict__ W,
                                                 bf16* __restrict__ dtp,
                                                 float* __restrict__ bcp) {
  __shared__ float Lred[4][16 * LPAD];   // 41,984 B
  const int tid = threadIdx.x;
  const int w = tid >> 6;                // 0..7
  const int lane = tid & 63;
  const int m = lane & 15;
  const int q = lane >> 4;
  const int row0 = blockIdx.x * 16;
  const int ks = blockIdx.y;
  const int k0 = ks * (DI / KSP) + w * 64;

  f32x4 acc[10] = {};
  const float* ap = x + (size_t)(row0 + m) * DI + k0 + 8 * q;
  const float* wp = W + (size_t)m * DI + k0 + 8 * q;

#pragma unroll
  for (int kk = 0; kk < 64; kk += 32) {
    float4 a0 = *(const float4*)(ap + kk);
    float4 a1 = *(const float4*)(ap + kk + 4);
    bf16x8 af = cvt8(a0, a1);
#pragma unroll
    for (int nt = 0; nt < 10; ++nt) {
      const float* wq = wp + (size_t)nt * 16 * DI + kk;
      float4 b0 = *(const float4*)(wq);
      float4 b1 = *(const float4*)(wq + 4);
      acc[nt] = __builtin_amdgcn_mfma_f32_16x16x32_bf16(af, cvt8(b0, b1), acc[nt], 0, 0, 0);
    }
  }

  // C/D layout: col = m (N dim), row = 4q + r (M dim). Two-stage reduce.
  if (w < 4) {
#pragma unroll
    for (int nt = 0; nt < 10; ++nt)
#pragma unroll
      for (int r = 0; r < 4; ++r)
        Lred[w][(4 * q + r) * LPAD + nt * 16 + m] = acc[nt][r];
  }
  __syncthreads();
  if (w >= 4) {
#pragma unroll
    for (int nt = 0; nt < 10; ++nt)
#pragma unroll
      for (int r = 0; r < 4; ++r)
        Lred[w - 4][(4 * q + r) * LPAD + nt * 16 + m] += acc[nt][r];
  }
  __syncthreads();

#pragma unroll
  for (int i = 0; i < 5; ++i) {
    const int o = i * 512 + tid;           // 0..2559 over 16x160 outputs
    const int row = o / 160;
    const int col = o - row * 160;
    const int a = row * LPAD + col;
    const float s = Lred[0][a] + Lred[1][a] + Lred[2][a] + Lred[3][a];
    if (col < RDT) dtp[(size_t)ks * (BL * RDT) + (size_t)(row0 + row) * RDT + col] = (bf16)s;
    else           bcp[(size_t)ks * (BL * 32) + (size_t)(row0 + row) * 32 + (col - RDT)] = s;
  }
}

// ---------------------------------------------------------------------------
// Fold the 8 k-split slabs into the scan's compact inputs:
//   dtin bf16 [1024][128], BCf fp32 [1024][32].
// 160 blocks x 256 threads, 4 outputs/thread; ~12 MB L2-resident reads.
// ---------------------------------------------------------------------------
__global__ __launch_bounds__(256) void reduce_slabs(const bf16* __restrict__ dtp,
                                                    const float* __restrict__ bcp,
                                                    bf16* __restrict__ dtin,
                                                    float* __restrict__ BCf) {
  const int o = (blockIdx.x * 256 + threadIdx.x) * 4;
  const int row = o / RTOT;
  const int col = o - row * RTOT;   // multiple of 4; never straddles rows
  if (col < RDT) {
    float s0 = 0.f, s1 = 0.f, s2 = 0.f, s3 = 0.f;
#pragma unroll
    for (int ks = 0; ks < KSP; ++ks) {
      bf16x4 v = *(const bf16x4*)(dtp + (size_t)ks * (BL * RDT) + (size_t)row * RDT + col);
      s0 += (float)v[0]; s1 += (float)v[1]; s2 += (float)v[2]; s3 += (float)v[3];
    }
    bf16x4 ob;
    ob[0] = (bf16)s0; ob[1] = (bf16)s1; ob[2] = (bf16)s2; ob[3] = (bf16)s3;
    *(bf16x4*)(dtin + (size_t)row * RDT + col) = ob;
  } else {
    float4 s = make_float4(0.f, 0.f, 0.f, 0.f);
#pragma unroll
    for (int ks = 0; ks < KSP; ++ks) {
      float4 v = *(const float4*)&bcp[(size_t)ks * (BL * 32) + (size_t)row * 32 + (col - RDT)];
      s.x += v.x; s.y += v.y; s.z += v.z; s.w += v.w;
    }
    *(float4*)&BCf[(size_t)row * 32 + (col - RDT)] = s;
  }
}

// ---------------------------------------------------------------------------
// 16-lane (DPP row) sum reduction on the VALU pipe. Result valid in lane 15
// of each 16-lane row.
// ---------------------------------------------------------------------------
__device__ __forceinline__ float row16_reduce_add(float p) {
  p += __int_as_float(__builtin_amdgcn_update_dpp(
      0, __float_as_int(p), 0x111, 0xf, 0xf, true));  // row_shr:1
  p += __int_as_float(__builtin_amdgcn_update_dpp(
      0, __float_as_int(p), 0x112, 0xf, 0xf, true));  // row_shr:2
  p += __int_as_float(__builtin_amdgcn_update_dpp(
      0, __float_as_int(p), 0x114, 0xf, 0xf, true));  // row_shr:4
  p += __int_as_float(__builtin_amdgcn_update_dpp(
      0, __float_as_int(p), 0x118, 0xf, 0xf, true));  // row_shr:8
  return p;
}

// ---------------------------------------------------------------------------
// Fused GEMM2 + selective scan.
// Round-5 structure plus:
//  - uS = softplus(dt)*x staged ONCE per (d,t) (was computed 16x redundantly
//    in the core: u = dt*x*B -> u = uS*B, -8 muls/group). MFMA threads load
//    their own 4 x elements (prefetched; 32 KB/block, L2-hot).
//  - g-loop unrolled (constant-folds LDS offsets into immediates).
//  - s_setprio(1) around the serial core (independent blocks per CU).
// ---------------------------------------------------------------------------
#define TC  64
#define TCP 68
#define NCH (SEQLEN / TC)

__global__ __launch_bounds__(256) void scan_fused(const float* __restrict__ x,
                                                  const float* __restrict__ A_log,
                                                  const float* __restrict__ Dvec,
                                                  const float* __restrict__ BCf,
                                                  const bf16* __restrict__ dtin,
                                                  const float* __restrict__ dtw,
                                                  const float* __restrict__ dtb,
                                                  float* __restrict__ out) {
  __shared__ __align__(16) float dtS[16][TCP];  // [dc][t]  softplus(dt)
  __shared__ __align__(16) float uS[16][TCP];   // [dc][t]  softplus(dt)*x
  __shared__ __align__(16) float BS[16][TCP];   // [n][t]
  __shared__ __align__(16) float CS[16][TCP];   // [n][t]
  __shared__ __align__(16) float yS[TC][16];    // [t][dc]

  const int bid = blockIdx.x;         // 0..511
  const int b = bid >> 8;
  const int d0 = (bid & 255) * 16;
  const int tid = threadIdx.x;
  const int n = tid & 15;             // state (scan) / MFMA m
  const int dc = tid >> 4;            // channel (scan)
  const int d = d0 + dc;
  const int w = tid >> 6;             // wave id (MFMA staging)
  const int m = tid & 15;
  const int q = (tid >> 4) & 3;

  const float A2 = -LOG2E * __expf(A_log[d * DS + n]);   // exp2-folded A
  const float bias2 = dtb[d0 + m] * LOG2E;

  // dtw B-fragments: chunk-invariant, scaled by log2e, cast inline (once)
  bf16x8 bfragW[4];
#pragma unroll
  for (int k = 0; k < 4; ++k) {
    const float* p = dtw + (size_t)(d0 + m) * RDT + 32 * k + 8 * q;
    float4 w0 = *(const float4*)p;
    float4 w1 = *(const float4*)(p + 4);
    bfragW[k] = cvt8s(w0, w1, LOG2E);
  }

  // loader mapping for B/C/y: thread -> row lt (0..63), 4-elem slice lf
  const int lt = tid >> 2;
  const int lf = (tid & 3) * 4;
  const int rowbase = b * SEQLEN;
  const float4 Dv4 = *(const float4*)&Dvec[d0 + lf];  // for deferred D*x

  // MFMA-thread x rows: t = 16w + 4q + r within chunk (matches D layout)
  const int xtrow = rowbase + 16 * w + 4 * q;

  // prefetch chunk 0
  bf16x8 afrag[4];
  float xm[4];
  float4 rx, rB, rC, rx_prev;
  {
    const int arow = rowbase + 16 * w + m;
#pragma unroll
    for (int k = 0; k < 4; ++k)
      afrag[k] = *(const bf16x8*)(dtin + (size_t)arow * RDT + 32 * k + 8 * q);
#pragma unroll
    for (int r = 0; r < 4; ++r)
      xm[r] = x[(size_t)(xtrow + r) * DI + d0 + m];
    const int row = rowbase + lt;
    rx = *(const float4*)&x[(size_t)row * DI + d0 + lf];
    rB = *(const float4*)&BCf[row * 32 + lf];
    rC = *(const float4*)&BCf[row * 32 + 16 + lf];
  }

  float h = 0.f;

  for (int c = 0; c < NCH; ++c) {
    if (c > 0) __syncthreads();   // prev compute (LDS reads + yS writes) done

    // ---- stage dt & u via MFMA + softplus (log2 domain) ----
    {
      f32x4 acc = {};
#pragma unroll
      for (int k = 0; k < 4; ++k)
        acc = __builtin_amdgcn_mfma_f32_16x16x32_bf16(afrag[k], bfragW[k], acc, 0, 0, 0);
      // D layout: col m = channel, row 4q+r = timestep within 16-row tile
#pragma unroll
      for (int r = 0; r < 4; ++r) {
        const float z2 = acc[r] + bias2;             // = z * log2(e)
        const float dts =
            (z2 > 28.854f) ? z2 * LN2
                           : LN2 * __builtin_amdgcn_logf(1.f + __builtin_amdgcn_exp2f(z2));
        dtS[m][16 * w + 4 * q + r] = dts;
        uS[m][16 * w + 4 * q + r] = dts * xm[r];
      }
    }
    // ---- stage B, C (transposed) ----
    {
      const float rBa[4] = {rB.x, rB.y, rB.z, rB.w};
      const float rCa[4] = {rC.x, rC.y, rC.z, rC.w};
#pragma unroll
      for (int j = 0; j < 4; ++j) {
        BS[lf + j][lt] = rBa[j];
        CS[lf + j][lt] = rCa[j];
      }
    }
    // ---- store previous chunk's y (+ deferred D*x via rx_prev) ----
    if (c > 0) {
      const int prow = rowbase + (c - 1) * TC + lt;
      float4 yv = *(const float4*)&yS[lt][lf];
      float4 o4;
      o4.x = fmaf(Dv4.x, rx_prev.x, yv.x);
      o4.y = fmaf(Dv4.y, rx_prev.y, yv.y);
      o4.z = fmaf(Dv4.z, rx_prev.z, yv.z);
      o4.w = fmaf(Dv4.w, rx_prev.w, yv.w);
      *(float4*)&out[(size_t)prow * DI + d0 + lf] = o4;
    }
    rx_prev = rx;                 // keep chunk c's x for its y-store

    __syncthreads();              // tiles ready; yS reads done

    // ---- prefetch next chunk ----
    if (c < NCH - 1) {
      const int arow = rowbase + (c + 1) * TC + 16 * w + m;
#pragma unroll
      for (int k = 0; k < 4; ++k)
        afrag[k] = *(const bf16x8*)(dtin + (size_t)arow * RDT + 32 * k + 8 * q);
#pragma unroll
      for (int r = 0; r < 4; ++r)
        xm[r] = x[(size_t)(xtrow + (c + 1) * TC + r) * DI + d0 + m];
      const int row = rowbase + (c + 1) * TC + lt;
      rx = *(const float4*)&x[(size_t)row * DI + d0 + lf];
      rB = *(const float4*)&BCf[row * 32 + lf];
      rC = *(const float4*)&BCf[row * 32 + 16 + lf];
    }

    // ---- 64 steps: 8 groups of 8, fully unrolled register batches ----
    __builtin_amdgcn_s_setprio(1);
#pragma unroll
    for (int g = 0; g < 8; ++g) {
      const int t0 = 8 * g;
      const float4 dv0 = *(const float4*)&dtS[dc][t0];
      const float4 dv1 = *(const float4*)&dtS[dc][t0 + 4];
      const float4 uv0 = *(const float4*)&uS[dc][t0];
      const float4 uv1 = *(const float4*)&uS[dc][t0 + 4];
      const float4 Bv0 = *(const float4*)&BS[n][t0];
      const float4 Bv1 = *(const float4*)&BS[n][t0 + 4];
      const float4 Cv0 = *(const float4*)&CS[n][t0];
      const float4 Cv1 = *(const float4*)&CS[n][t0 + 4];
      const float dt[8] = {dv0.x, dv0.y, dv0.z, dv0.w, dv1.x, dv1.y, dv1.z, dv1.w};
      const float uv[8] = {uv0.x, uv0.y, uv0.z, uv0.w, uv1.x, uv1.y, uv1.z, uv1.w};
      const float Bv[8] = {Bv0.x, Bv0.y, Bv0.z, Bv0.w, Bv1.x, Bv1.y, Bv1.z, Bv1.w};
      const float Cv[8] = {Cv0.x, Cv0.y, Cv0.z, Cv0.w, Cv1.x, Cv1.y, Cv1.z, Cv1.w};

      float e[8], u[8], p[8];
#pragma unroll
      for (int j = 0; j < 8; ++j) {       // independent: pipelines freely
        e[j] = __builtin_amdgcn_exp2f(dt[j] * A2);   // 1 mul + v_exp_f32
        u[j] = uv[j] * Bv[j];             // dt*x pre-staged: 1 mul
      }
#pragma unroll
      for (int j = 0; j < 8; ++j) {       // the only true serial chain
        h = fmaf(e[j], h, u[j]);
        p[j] = h * Cv[j];
      }
#pragma unroll
      for (int j = 0; j < 8; ++j)         // 8 independent DPP chains
        p[j] = row16_reduce_add(p[j]);
      if (n == 15) {
#pragma unroll
        for (int j = 0; j < 8; ++j)
          yS[t0 + j][dc] = p[j];          // D*x applied at store time
      }
    }
    __builtin_amdgcn_s_setprio(0);
  }

  __syncthreads();
  {
    const int prow = rowbase + (NCH - 1) * TC + lt;
    float4 yv = *(const float4*)&yS[lt][lf];
    float4 o4;
    o4.x = fmaf(Dv4.x, rx_prev.x, yv.x);
    o4.y = fmaf(Dv4.y, rx_prev.y, yv.y);
    o4.z = fmaf(Dv4.z, rx_prev.z, yv.z);
    o4.w = fmaf(Dv4.w, rx_prev.w, yv.w);
    *(float4*)&out[(size_t)prow * DI + d0 + lf] = o4;
  }
}

// ---------------------------------------------------------------------------
extern "C" void kernel_launch(void* const* d_in, const int* in_sizes, int n_in,
                              void* d_out, int out_size, void* d_ws, size_t ws_size,
                              hipStream_t stream) {
  const float* x     = (const float*)d_in[0];  // (2,512,4096)
  const float* A_log = (const float*)d_in[1];  // (4096,16)
  const float* Dv    = (const float*)d_in[2];  // (4096,)
  const float* W     = (const float*)d_in[3];  // (160,4096)
  const float* dtw   = (const float*)d_in[4];  // (4096,128)
  const float* dtb   = (const float*)d_in[5];  // (4096,)
  float* out = (float*)d_out;

  // Workspace: dtp [8][1024][128] bf16 (2 MB) + bcp [8][1024][32] f32 (1 MB)
  //          + dtin [1024][128] bf16 (256 KB) + BCf [1024][32] f32 (128 KB)
  char* ws = (char*)d_ws;
  bf16*  dtp  = (bf16*)ws;
  float* bcp  = (float*)(ws + (size_t)KSP * BL * RDT * sizeof(bf16));
  bf16*  dtin = (bf16*)(ws + (size_t)KSP * BL * RDT * sizeof(bf16)
                           + (size_t)KSP * BL * 32 * sizeof(float));
  float* BCf  = (float*)(ws + (size_t)KSP * BL * RDT * sizeof(bf16)
                            + (size_t)KSP * BL * 32 * sizeof(float)
                            + (size_t)BL * RDT * sizeof(bf16));

  gemm_part<<<dim3(64, KSP), 512, 0, stream>>>(x, W, dtp, bcp);
  reduce_slabs<<<dim3(160), 256, 0, stream>>>(dtp, bcp, dtin, BCf);
  scan_fused<<<dim3(512), 256, 0, stream>>>(x, A_log, Dv, BCf, dtin, dtw, dtb, out);
}